// Round 20
// baseline (714.292 us; speedup 1.0000x reference)
//
#include <hip/hip_runtime.h>

// AttentionHead: B=16384, W=10, D=1024, K=V=64
// out[b,i,:] = softmax_j( min(k_i . q_j, tri) ) @ v    (scores row = key index)
//
// GEMM front-end: 3-term split-FP16 MFMA. x = xh + xl*2^-11, w = wh + wl*2^-11
// (residuals pre-scaled by 2^11 -> fp16 normal range). f64-dot epilogue; f32 out.
//
// Round-20 (R19 + compile fix: cvt_pkrtz returns __fp16x2 -> take via auto +
// bit_cast). On the champion R14 structure (dbuf LDS, 1 barrier/chunk,
// issue-early x prefetch, 3 blocks/CU):
//  (1) cross-terms accumulate into a PERSISTENT acc2[5][3] folded ONCE at the
//      epilogue (acc + 2^-11*acc2) -- removes the per-triple zero-init + 4-FMA
//      fold (~240 VALU inst/wave/chunk). +60 VGPR, under the 3-block cap.
//  (2) packed v_cvt_pkrtz conversion (2 elems/inst) in staging.

#define D 1024
#define BM 80            // 8 batches of 10 rows per block
#define KCHUNKS 16       // 1024 / 64
#define ASTR 72          // staged row stride in shorts (64 data + 8 pad)
#define APIECE 11520     // bytes per staged piece [80][ASTR]
#define ABUF 23040       // bytes per staging buffer (2 pieces)
#define KQSTR 133        // kq row stride (floats)
#define VSTR 65          // v row stride (floats), overlay
#define SCOFF 42560      // byte offset of score buffer
#define SMEMSZ 46080     // 42560 + 4*220*4 == 2*ABUF
#define SCL 4.8828125e-4f   // 2^-11

typedef __attribute__((ext_vector_type(8))) _Float16 f16x8;
typedef __attribute__((ext_vector_type(4))) float f32x4;
typedef __attribute__((ext_vector_type(4))) unsigned short u16x4;

// split 2 f32 into packed fp16 hi + pre-scaled fp16 lo (packed RTZ converts)
static __device__ __forceinline__ void split2(float a, float b,
                                              unsigned int& hs, unsigned int& ls) {
    auto hv = __builtin_amdgcn_cvt_pkrtz(a, b);       // __fp16 ext_vector(2)
    float ra = (a - (float)hv[0]) * 2048.0f;
    float rb = (b - (float)hv[1]) * 2048.0f;
    auto lv = __builtin_amdgcn_cvt_pkrtz(ra, rb);
    hs = __builtin_bit_cast(unsigned int, hv);
    ls = __builtin_bit_cast(unsigned int, lv);
}

// --- kernel0: split wk|wq|wv into transposed fp16 2-piece Wt[n][k]
__global__ __launch_bounds__(256) void prep_w(const float* __restrict__ wk,
                                              const float* __restrict__ wq,
                                              const float* __restrict__ wv,
                                              unsigned short* __restrict__ wth,
                                              unsigned short* __restrict__ wtl) {
    int idx = blockIdx.x * 256 + threadIdx.x;   // idx = n*1024 + kk, n in [0,192)
    int n  = idx >> 10;
    int kk = idx & 1023;
    const float* src = (n < 64) ? wk : (n < 128) ? wq : wv;
    float w = src[kk * 64 + (n & 63)];
    _Float16 h = (_Float16)w;
    float r = (w - (float)h) * 2048.0f;         // pre-scaled residual
    _Float16 l = (_Float16)r;
    wth[idx] = __builtin_bit_cast(unsigned short, h);
    wtl[idx] = __builtin_bit_cast(unsigned short, l);
}

// --- kernel1: fused 3-term fp16 projection GEMM + attention
__global__ __launch_bounds__(256, 3) void fused_attn(
        const float* __restrict__ x,
        const unsigned short* __restrict__ wth,
        const unsigned short* __restrict__ wtl,
        float* __restrict__ out) {

    __shared__ char smem[SMEMSZ];
    float* kq  = (float*)smem;                   // [80][KQSTR] = 42560 B
    float* vv  = (float*)smem;                   // [80][VSTR] overlay
    float* scw = (float*)(smem + SCOFF);         // [4][220] f32 probs

    const int tid  = threadIdx.x;
    const int wave = tid >> 6;
    const int lane = tid & 63;
    const int m0   = blockIdx.x * BM;
    const int nbase = wave * 48;          // 3 n-tiles of 16 per wave (192 total)
    const int arow  = lane & 15;
    const int apart = lane >> 4;          // 0..3

    // ---------- layout probe (register-only): acc (lane,reg) -> (row, col) ----
    f16x8 aprobe = {}, bone = {}, aone = {}, bcol = {};
    if (apart == 0) {
        aprobe[0] = (_Float16)(float)(arow + 1);  // A[m][0] = m+1
        bone[0]   = (_Float16)1.0f;               // B[0][n] = 1
        aone[0]   = (_Float16)1.0f;               // A[m][0] = 1
        bcol[0]   = (_Float16)(float)(arow + 1);  // B[0][n] = n+1
    }
    f32x4 z = {0.f, 0.f, 0.f, 0.f};
    f32x4 d1 = __builtin_amdgcn_mfma_f32_16x16x32_f16(aprobe, bone, z, 0, 0, 0); // row+1
    f32x4 d2 = __builtin_amdgcn_mfma_f32_16x16x32_f16(aone,  bcol, z, 0, 0, 0);  // col+1
    int R[4], Cc[4];
    #pragma unroll
    for (int r = 0; r < 4; ++r) {
        R[r]  = (int)(d1[r] + 0.5f) - 1;
        Cc[r] = (int)(d2[r] + 0.5f) - 1;
    }

    // per-thread staging coords (p = tid + it*256 -> row, col)
    int srow[5], scol[5];
    #pragma unroll
    for (int it = 0; it < 5; ++it) {
        int p = tid + it * 256;
        srow[it] = p >> 4;
        scol[it] = (p & 15) << 2;
    }

    // ---------- GEMM: kqv[80][192] = x @ [wk|wq|wv], 3-term fp16 split -------
    f32x4 acc[5][3]  = {};                // main (hh) accumulator
    f32x4 acc2[5][3] = {};                // cross-term accumulator (x 2^-11)

    // prologue: stage chunk 0 into buffer 0
    {
        float4 xv[5];
        #pragma unroll
        for (int it = 0; it < 5; ++it)
            xv[it] = *reinterpret_cast<const float4*>(
                x + (size_t)(m0 + srow[it]) * D + scol[it]);
        unsigned short* H = (unsigned short*)smem;
        unsigned short* L = (unsigned short*)(smem + APIECE);
        #pragma unroll
        for (int it = 0; it < 5; ++it) {
            unsigned int h01, l01, h23, l23;
            split2(xv[it].x, xv[it].y, h01, l01);
            split2(xv[it].z, xv[it].w, h23, l23);
            u16x4 hh = __builtin_bit_cast(u16x4, uint2{h01, h23});
            u16x4 ll = __builtin_bit_cast(u16x4, uint2{l01, l23});
            int ro = srow[it] * ASTR + scol[it];
            *reinterpret_cast<u16x4*>(H + ro) = hh;
            *reinterpret_cast<u16x4*>(L + ro) = ll;
        }
    }
    __syncthreads();

    for (int t = 0; t < KCHUNKS; ++t) {
        char* curb = smem + (t & 1) * ABUF;
        char* nxtb = smem + ((t + 1) & 1) * ABUF;

        // issue next chunk's x loads EARLY (latency hides under MFMA phase)
        float4 xv[5];
        if (t < KCHUNKS - 1) {
            #pragma unroll
            for (int it = 0; it < 5; ++it)
                xv[it] = *reinterpret_cast<const float4*>(
                    x + (size_t)(m0 + srow[it]) * D + (t + 1) * 64 + scol[it]);
        }

        // MFMA phase on staged chunk t
        #pragma unroll
        for (int ks = 0; ks < 2; ++ks) {
            f16x8 wfh[3], wfl[3];
            #pragma unroll
            for (int nt = 0; nt < 3; ++nt) {
                int n = nbase + nt * 16 + arow;
                size_t off = (size_t)n * D + t * 64 + ks * 32 + apart * 8;
                wfh[nt] = *reinterpret_cast<const f16x8*>(wth + off);
                wfl[nt] = *reinterpret_cast<const f16x8*>(wtl + off);
            }
            #pragma unroll
            for (int mt = 0; mt < 5; ++mt) {
                int ab = (mt * 16 + arow) * (ASTR * 2) + (ks * 4 + apart) * 16;
                f16x8 ah = *reinterpret_cast<const f16x8*>(curb + ab);
                f16x8 al = *reinterpret_cast<const f16x8*>(curb + APIECE + ab);
                #pragma unroll
                for (int nt = 0; nt < 3; ++nt) {
                    acc[mt][nt]  = __builtin_amdgcn_mfma_f32_16x16x32_f16(ah, wfh[nt], acc[mt][nt],  0, 0, 0);
                    acc2[mt][nt] = __builtin_amdgcn_mfma_f32_16x16x32_f16(ah, wfl[nt], acc2[mt][nt], 0, 0, 0);
                    acc2[mt][nt] = __builtin_amdgcn_mfma_f32_16x16x32_f16(al, wfh[nt], acc2[mt][nt], 0, 0, 0);
                }
            }
        }

        // convert + write next chunk into the OTHER buffer (write-late)
        if (t < KCHUNKS - 1) {
            unsigned short* H = (unsigned short*)nxtb;
            unsigned short* L = (unsigned short*)(nxtb + APIECE);
            #pragma unroll
            for (int it = 0; it < 5; ++it) {
                unsigned int h01, l01, h23, l23;
                split2(xv[it].x, xv[it].y, h01, l01);
                split2(xv[it].z, xv[it].w, h23, l23);
                u16x4 hh = __builtin_bit_cast(u16x4, uint2{h01, h23});
                u16x4 ll = __builtin_bit_cast(u16x4, uint2{l01, l23});
                int ro = srow[it] * ASTR + scol[it];
                *reinterpret_cast<u16x4*>(H + ro) = hh;
                *reinterpret_cast<u16x4*>(L + ro) = ll;
            }
        }
        __syncthreads();   // one barrier per chunk: next buf ready, cur buf free
    }

    // ---------- epilogue: two-phase (kq -> scores -> v overlay -> PV) ----------
    // phase 1: dump k,q columns (col < 128), folding acc2 once
    #pragma unroll
    for (int mt = 0; mt < 5; ++mt) {
        #pragma unroll
        for (int r = 0; r < 4; ++r) {
            int row = mt * 16 + R[r];
            #pragma unroll
            for (int nt = 0; nt < 3; ++nt) {
                int colbase = nbase + nt * 16;
                if (colbase < 128)
                    kq[row * KQSTR + colbase + Cc[r]] =
                        fmaf(acc2[mt][nt][r], SCL, acc[mt][nt][r]);
            }
        }
    }
    __syncthreads();

    // phase 2: masked scores for both batches of this wave (f64 dots, f32 store)
    float* sc0 = scw + wave * 220;
    #pragma unroll
    for (int bb = 0; bb < 2; ++bb) {
        const int r0 = (wave * 2 + bb) * 10;
        float* sc = sc0 + bb * 110;
        #pragma unroll
        for (int it = 0; it < 2; ++it) {
            int p = it * 64 + lane;
            if (p < 100) {
                int i = p / 10;
                int j = p - i * 10;
                double s = 0.0;
                #pragma unroll 8
                for (int c = 0; c < 64; ++c)
                    s += (double)kq[(r0 + i) * KQSTR + c] *
                         (double)kq[(r0 + j) * KQSTR + 64 + c];
                double lim = (j <= i) ? 1e5 : -1e5;
                sc[i * 11 + j] = (float)fmin(s, lim);
            }
        }
    }
    __syncthreads();   // kq reads done -> safe to overlay v

    // phase 3: softmax (lanes 0-9, f64 from f32 scores) + v dump (cols >= 128)
    if (lane < 10) {
        int i = lane;
        #pragma unroll
        for (int bb = 0; bb < 2; ++bb) {
            float* sc = sc0 + bb * 110;
            double vals[10];
            double mx = -1e300;
            #pragma unroll
            for (int j = 0; j < 10; ++j) { vals[j] = (double)sc[i * 11 + j]; mx = fmax(mx, vals[j]); }
            double sum = 0.0;
            #pragma unroll
            for (int j = 0; j < 10; ++j) { vals[j] = exp(vals[j] - mx); sum += vals[j]; }
            double inv = 1.0 / sum;
            #pragma unroll
            for (int j = 0; j < 10; ++j) sc[i * 11 + j] = (float)(vals[j] * inv);
        }
    }
    #pragma unroll
    for (int mt = 0; mt < 5; ++mt) {
        #pragma unroll
        for (int r = 0; r < 4; ++r) {
            int row = mt * 16 + R[r];
            #pragma unroll
            for (int nt = 0; nt < 3; ++nt) {
                int colbase = nbase + nt * 16;
                if (colbase >= 128)
                    vv[row * VSTR + (colbase - 128) + Cc[r]] =
                        fmaf(acc2[mt][nt][r], SCL, acc[mt][nt][r]);
            }
        }
    }
    __syncthreads();

    // phase 4: PV (f64 accum, f32 probs/v) + f32 store; lane = output column
    #pragma unroll
    for (int bb = 0; bb < 2; ++bb) {
        const int bloc = wave * 2 + bb;
        const int r0   = bloc * 10;
        float* sc = sc0 + bb * 110;
        size_t ob = (size_t)(blockIdx.x * 8 + bloc) * 640;
        #pragma unroll
        for (int i = 0; i < 10; ++i) {
            double o = 0.0;
            #pragma unroll
            for (int j = 0; j < 10; ++j)
                o += (double)sc[i * 11 + j] * (double)vv[(r0 + j) * VSTR + lane];
            out[ob + (size_t)i * 64 + lane] = (float)o;
        }
    }
}

extern "C" void kernel_launch(void* const* d_in, const int* in_sizes, int n_in,
                              void* d_out, int out_size, void* d_ws, size_t ws_size,
                              hipStream_t stream) {
    const float* x  = (const float*)d_in[0];
    const float* wk = (const float*)d_in[1];
    const float* wq = (const float*)d_in[2];
    const float* wv = (const float*)d_in[3];
    unsigned short* wth = (unsigned short*)d_ws;          // 2 x 192*1024 fp16
    unsigned short* wtl = wth + 192 * 1024;
    float* outp = (float*)d_out;                          // FLOAT32 output

    prep_w<<<768, 256, 0, stream>>>(wk, wq, wv, wth, wtl);
    fused_attn<<<2048, 256, 0, stream>>>(x, wth, wtl, outp);
}

// Round 21
// 305.918 us; speedup vs baseline: 2.3349x; 2.3349x over previous
//
#include <hip/hip_runtime.h>

// AttentionHead: B=16384, W=10, D=1024, K=V=64
// out[b,i,:] = softmax_j( min(k_i . q_j, tri) ) @ v    (scores row = key index)
//
// CHAMPION (R14 verbatim, 310us): 3-term split-FP16 MFMA front-end.
// x = xh + xl*2^-11, w = wh + wl*2^-11 (residuals pre-scaled by 2^11 into the
// fp16 normal range -> no denormal risk). k = xh*wh + (xh*wl + xl*wh)*2^-11;
// dropped ll term ~2^-22. Cross terms via zero-init f32x4 temp (2 MFMAs)
// folded by 4 FMAs -- R20 proved a persistent acc2 spills to scratch at
// this occupancy (FETCH 643MB / WRITE 714MB), so the temp is optimal.
// f64-dot attention epilogue; FLOAT32 output.
// Structure: LDS double-buffer (2x23KB), ONE barrier per chunk, issue-early
// x prefetch, 3 blocks/CU. All other orchestration levers measured null or
// negative (R8,R11,R13,R15,R16,R17,R18,R20) -- this is the structure's
// practical plateau (~9.3x over the correct f64 baseline).

#define D 1024
#define BM 80            // 8 batches of 10 rows per block
#define KCHUNKS 16       // 1024 / 64
#define ASTR 72          // staged row stride in shorts (64 data + 8 pad)
#define APIECE 11520     // bytes per staged piece [80][ASTR]
#define ABUF 23040       // bytes per staging buffer (2 pieces)
#define KQSTR 133        // kq row stride (floats)
#define VSTR 65          // v row stride (floats), overlay
#define SCOFF 42560      // byte offset of score buffer
#define SMEMSZ 46080     // 42560 + 4*220*4 == 2*ABUF
#define SCL 4.8828125e-4f   // 2^-11

typedef __attribute__((ext_vector_type(8))) _Float16 f16x8;
typedef __attribute__((ext_vector_type(4))) float f32x4;
typedef __attribute__((ext_vector_type(4))) unsigned short u16x4;

// --- kernel0: split wk|wq|wv into transposed fp16 2-piece Wt[n][k]
__global__ __launch_bounds__(256) void prep_w(const float* __restrict__ wk,
                                              const float* __restrict__ wq,
                                              const float* __restrict__ wv,
                                              unsigned short* __restrict__ wth,
                                              unsigned short* __restrict__ wtl) {
    int idx = blockIdx.x * 256 + threadIdx.x;   // idx = n*1024 + kk, n in [0,192)
    int n  = idx >> 10;
    int kk = idx & 1023;
    const float* src = (n < 64) ? wk : (n < 128) ? wq : wv;
    float w = src[kk * 64 + (n & 63)];
    _Float16 h = (_Float16)w;
    float r = (w - (float)h) * 2048.0f;         // pre-scaled residual
    _Float16 l = (_Float16)r;
    wth[idx] = __builtin_bit_cast(unsigned short, h);
    wtl[idx] = __builtin_bit_cast(unsigned short, l);
}

// --- kernel1: fused 3-term fp16 projection GEMM + attention
__global__ __launch_bounds__(256, 3) void fused_attn(
        const float* __restrict__ x,
        const unsigned short* __restrict__ wth,
        const unsigned short* __restrict__ wtl,
        float* __restrict__ out) {

    __shared__ char smem[SMEMSZ];
    // staging view: double buffer, each {hi[80][ASTR], lo[80][ASTR]} fp16
    // epilogue view
    float* kq  = (float*)smem;                   // [80][KQSTR] = 42560 B
    float* vv  = (float*)smem;                   // [80][VSTR] overlay
    float* scw = (float*)(smem + SCOFF);         // [4][220] f32 probs

    const int tid  = threadIdx.x;
    const int wave = tid >> 6;
    const int lane = tid & 63;
    const int m0   = blockIdx.x * BM;
    const int nbase = wave * 48;          // 3 n-tiles of 16 per wave (192 total)
    const int arow  = lane & 15;
    const int apart = lane >> 4;          // 0..3

    // ---------- layout probe (register-only): acc (lane,reg) -> (row, col) ----
    f16x8 aprobe = {}, bone = {}, aone = {}, bcol = {};
    if (apart == 0) {
        aprobe[0] = (_Float16)(float)(arow + 1);  // A[m][0] = m+1
        bone[0]   = (_Float16)1.0f;               // B[0][n] = 1
        aone[0]   = (_Float16)1.0f;               // A[m][0] = 1
        bcol[0]   = (_Float16)(float)(arow + 1);  // B[0][n] = n+1
    }
    f32x4 z = {0.f, 0.f, 0.f, 0.f};
    f32x4 d1 = __builtin_amdgcn_mfma_f32_16x16x32_f16(aprobe, bone, z, 0, 0, 0); // row+1
    f32x4 d2 = __builtin_amdgcn_mfma_f32_16x16x32_f16(aone,  bcol, z, 0, 0, 0);  // col+1
    int R[4], Cc[4];
    #pragma unroll
    for (int r = 0; r < 4; ++r) {
        R[r]  = (int)(d1[r] + 0.5f) - 1;
        Cc[r] = (int)(d2[r] + 0.5f) - 1;
    }

    // per-thread staging coords (p = tid + it*256 -> row, col)
    int srow[5], scol[5];
    #pragma unroll
    for (int it = 0; it < 5; ++it) {
        int p = tid + it * 256;
        srow[it] = p >> 4;
        scol[it] = (p & 15) << 2;
    }

    // ---------- GEMM: kqv[80][192] = x @ [wk|wq|wv], 3-term fp16 split -------
    f32x4 acc[5][3] = {};                 // 5 m-tiles x 3 n-tiles

    // prologue: stage chunk 0 into buffer 0
    {
        float4 xv[5];
        #pragma unroll
        for (int it = 0; it < 5; ++it)
            xv[it] = *reinterpret_cast<const float4*>(
                x + (size_t)(m0 + srow[it]) * D + scol[it]);
        unsigned short* H = (unsigned short*)smem;
        unsigned short* L = (unsigned short*)(smem + APIECE);
        #pragma unroll
        for (int it = 0; it < 5; ++it) {
            u16x4 hh, ll;
            #pragma unroll
            for (int e = 0; e < 4; ++e) {
                float xe = (e == 0) ? xv[it].x : (e == 1) ? xv[it].y : (e == 2) ? xv[it].z : xv[it].w;
                _Float16 h = (_Float16)xe;
                float rl = (xe - (float)h) * 2048.0f;
                _Float16 l = (_Float16)rl;
                hh[e] = __builtin_bit_cast(unsigned short, h);
                ll[e] = __builtin_bit_cast(unsigned short, l);
            }
            int ro = srow[it] * ASTR + scol[it];
            *reinterpret_cast<u16x4*>(H + ro) = hh;
            *reinterpret_cast<u16x4*>(L + ro) = ll;
        }
    }
    __syncthreads();

    for (int t = 0; t < KCHUNKS; ++t) {
        char* curb = smem + (t & 1) * ABUF;
        char* nxtb = smem + ((t + 1) & 1) * ABUF;

        // issue next chunk's x loads EARLY (latency hides under MFMA phase)
        float4 xv[5];
        if (t < KCHUNKS - 1) {
            #pragma unroll
            for (int it = 0; it < 5; ++it)
                xv[it] = *reinterpret_cast<const float4*>(
                    x + (size_t)(m0 + srow[it]) * D + (t + 1) * 64 + scol[it]);
        }

        // MFMA phase on staged chunk t
        #pragma unroll
        for (int ks = 0; ks < 2; ++ks) {
            f16x8 wfh[3], wfl[3];
            #pragma unroll
            for (int nt = 0; nt < 3; ++nt) {
                int n = nbase + nt * 16 + arow;
                size_t off = (size_t)n * D + t * 64 + ks * 32 + apart * 8;
                wfh[nt] = *reinterpret_cast<const f16x8*>(wth + off);
                wfl[nt] = *reinterpret_cast<const f16x8*>(wtl + off);
            }
            #pragma unroll
            for (int mt = 0; mt < 5; ++mt) {
                int ab = (mt * 16 + arow) * (ASTR * 2) + (ks * 4 + apart) * 16;
                f16x8 ah = *reinterpret_cast<const f16x8*>(curb + ab);
                f16x8 al = *reinterpret_cast<const f16x8*>(curb + APIECE + ab);
                #pragma unroll
                for (int nt = 0; nt < 3; ++nt) {
                    // main term
                    acc[mt][nt] = __builtin_amdgcn_mfma_f32_16x16x32_f16(ah, wfh[nt], acc[mt][nt], 0, 0, 0);
                    // cross terms at scale 2^-11 via zero-init temp + FMA fold
                    f32x4 tt = {0.f, 0.f, 0.f, 0.f};
                    tt = __builtin_amdgcn_mfma_f32_16x16x32_f16(ah, wfl[nt], tt, 0, 0, 0);
                    tt = __builtin_amdgcn_mfma_f32_16x16x32_f16(al, wfh[nt], tt, 0, 0, 0);
                    #pragma unroll
                    for (int c = 0; c < 4; ++c)
                        acc[mt][nt][c] = fmaf(tt[c], SCL, acc[mt][nt][c]);
                }
            }
        }

        // convert + write next chunk into the OTHER buffer (write-late)
        if (t < KCHUNKS - 1) {
            unsigned short* H = (unsigned short*)nxtb;
            unsigned short* L = (unsigned short*)(nxtb + APIECE);
            #pragma unroll
            for (int it = 0; it < 5; ++it) {
                u16x4 hh, ll;
                #pragma unroll
                for (int e = 0; e < 4; ++e) {
                    float xe = (e == 0) ? xv[it].x : (e == 1) ? xv[it].y : (e == 2) ? xv[it].z : xv[it].w;
                    _Float16 h = (_Float16)xe;
                    float rl = (xe - (float)h) * 2048.0f;
                    _Float16 l = (_Float16)rl;
                    hh[e] = __builtin_bit_cast(unsigned short, h);
                    ll[e] = __builtin_bit_cast(unsigned short, l);
                }
                int ro = srow[it] * ASTR + scol[it];
                *reinterpret_cast<u16x4*>(H + ro) = hh;
                *reinterpret_cast<u16x4*>(L + ro) = ll;
            }
        }
        __syncthreads();   // one barrier per chunk: next buf ready, cur buf free
    }

    // ---------- epilogue: two-phase (kq -> scores -> v overlay -> PV) ----------
    // phase 1: dump k,q columns (col < 128)
    #pragma unroll
    for (int mt = 0; mt < 5; ++mt) {
        #pragma unroll
        for (int r = 0; r < 4; ++r) {
            int row = mt * 16 + R[r];
            #pragma unroll
            for (int nt = 0; nt < 3; ++nt) {
                int colbase = nbase + nt * 16;
                if (colbase < 128)
                    kq[row * KQSTR + colbase + Cc[r]] = acc[mt][nt][r];
            }
        }
    }
    __syncthreads();

    // phase 2: masked scores for both batches of this wave (f64 dots, f32 store)
    float* sc0 = scw + wave * 220;
    #pragma unroll
    for (int bb = 0; bb < 2; ++bb) {
        const int r0 = (wave * 2 + bb) * 10;
        float* sc = sc0 + bb * 110;
        #pragma unroll
        for (int it = 0; it < 2; ++it) {
            int p = it * 64 + lane;
            if (p < 100) {
                int i = p / 10;
                int j = p - i * 10;
                double s = 0.0;
                #pragma unroll 8
                for (int c = 0; c < 64; ++c)
                    s += (double)kq[(r0 + i) * KQSTR + c] *
                         (double)kq[(r0 + j) * KQSTR + 64 + c];
                double lim = (j <= i) ? 1e5 : -1e5;
                sc[i * 11 + j] = (float)fmin(s, lim);
            }
        }
    }
    __syncthreads();   // kq reads done -> safe to overlay v

    // phase 3: softmax (lanes 0-9, f64 from f32 scores) + v dump (cols >= 128)
    if (lane < 10) {
        int i = lane;
        #pragma unroll
        for (int bb = 0; bb < 2; ++bb) {
            float* sc = sc0 + bb * 110;
            double vals[10];
            double mx = -1e300;
            #pragma unroll
            for (int j = 0; j < 10; ++j) { vals[j] = (double)sc[i * 11 + j]; mx = fmax(mx, vals[j]); }
            double sum = 0.0;
            #pragma unroll
            for (int j = 0; j < 10; ++j) { vals[j] = exp(vals[j] - mx); sum += vals[j]; }
            double inv = 1.0 / sum;
            #pragma unroll
            for (int j = 0; j < 10; ++j) sc[i * 11 + j] = (float)(vals[j] * inv);
        }
    }
    #pragma unroll
    for (int mt = 0; mt < 5; ++mt) {
        #pragma unroll
        for (int r = 0; r < 4; ++r) {
            int row = mt * 16 + R[r];
            #pragma unroll
            for (int nt = 0; nt < 3; ++nt) {
                int colbase = nbase + nt * 16;
                if (colbase >= 128)
                    vv[row * VSTR + (colbase - 128) + Cc[r]] = acc[mt][nt][r];
            }
        }
    }
    __syncthreads();

    // phase 4: PV (f64 accum, f32 probs/v) + f32 store; lane = output column
    #pragma unroll
    for (int bb = 0; bb < 2; ++bb) {
        const int bloc = wave * 2 + bb;
        const int r0   = bloc * 10;
        float* sc = sc0 + bb * 110;
        size_t ob = (size_t)(blockIdx.x * 8 + bloc) * 640;
        #pragma unroll
        for (int i = 0; i < 10; ++i) {
            double o = 0.0;
            #pragma unroll
            for (int j = 0; j < 10; ++j)
                o += (double)sc[i * 11 + j] * (double)vv[(r0 + j) * VSTR + lane];
            out[ob + (size_t)i * 64 + lane] = (float)o;
        }
    }
}

extern "C" void kernel_launch(void* const* d_in, const int* in_sizes, int n_in,
                              void* d_out, int out_size, void* d_ws, size_t ws_size,
                              hipStream_t stream) {
    const float* x  = (const float*)d_in[0];
    const float* wk = (const float*)d_in[1];
    const float* wq = (const float*)d_in[2];
    const float* wv = (const float*)d_in[3];
    unsigned short* wth = (unsigned short*)d_ws;          // 2 x 192*1024 fp16
    unsigned short* wtl = wth + 192 * 1024;
    float* outp = (float*)d_out;                          // FLOAT32 output

    prep_w<<<768, 256, 0, stream>>>(wk, wq, wv, wth, wtl);
    fused_attn<<<2048, 256, 0, stream>>>(x, wth, wtl, outp);
}